// Round 1
// baseline (325.580 us; speedup 1.0000x reference)
//
#include <hip/hip_runtime.h>
#include <hip/hip_bf16.h>

#define Bn 2
#define Sn 4096
#define Dn 256
#define Hn 8
#define KDn 256
#define DFFn 1024
#define Mn (Bn*Sn)          // 8192
#define NQKVn (Hn*KDn)      // 2048

typedef __attribute__((ext_vector_type(4))) float f32x4;
typedef __attribute__((ext_vector_type(8))) short bf16x8;
typedef __attribute__((ext_vector_type(4))) short short4v;

__device__ __forceinline__ short f2bf(float f) {
  unsigned u = __builtin_bit_cast(unsigned, f);
  unsigned r = u + 0x7fffu + ((u >> 16) & 1u);
  return (short)(r >> 16);
}

#define GLL16(gsrc, ldst) \
  __builtin_amdgcn_global_load_lds((const __attribute__((address_space(1))) void*)(gsrc), \
                                   (__attribute__((address_space(3))) void*)(ldst), 16, 0, 0)

// ---------------- convert x -> bf16 ----------------
__global__ __launch_bounds__(256)
void cvt_x(const float* __restrict__ x, short* __restrict__ xb, int n) {
  int i = (blockIdx.x * 256 + threadIdx.x) * 4;
  if (i < n) {
    float4 v = *(const float4*)(x + i);
    short4v o = { f2bf(v.x), f2bf(v.y), f2bf(v.z), f2bf(v.w) };
    *(short4v*)(xb + i) = o;
  }
}

// ---------------- transpose+convert weight: W(K,N) f32 -> WT(N,K) bf16 ----------------
__global__ __launch_bounds__(256)
void cvt_wT_tiled(const float* __restrict__ W, short* __restrict__ WT, int K, int N) {
  __shared__ short t[32][33];
  const int k0 = blockIdx.x * 32, n0 = blockIdx.y * 32;
  const int tx = threadIdx.x & 31, ty = threadIdx.x >> 5;  // ty 0..7
#pragma unroll
  for (int i = 0; i < 32; i += 8)
    t[ty + i][tx] = f2bf(W[(size_t)(k0 + ty + i) * N + n0 + tx]);
  __syncthreads();
#pragma unroll
  for (int i = 0; i < 32; i += 8)
    WT[(size_t)(n0 + ty + i) * K + k0 + tx] = t[tx][ty + i];
}

// ---------------- GEMM: C(MxN) = A(MxK,bf16) * BT(NxK,bf16)^T + bias ----------------
// MODE: 0 = f32 out, 1 = bf16 out, 2 = bf16 relu out, 3 = bf16 out transposed per-head (Vt)
template <int MODE>
__global__ __launch_bounds__(256, 2)
void gemm_bt(const short* __restrict__ A, const short* __restrict__ BT,
             const float* __restrict__ bias, void* __restrict__ Cout,
             int N, int K) {
  __shared__ __align__(16) short As[128 * 32];
  __shared__ __align__(16) short Bs[128 * 32];
  const int tid = threadIdx.x;
  const int lane = tid & 63;
  const int wave = tid >> 6;
  const int tm = blockIdx.x;
  const int tn = blockIdx.y;
  const int wr = (wave >> 1) * 64;
  const int wc = (wave & 1) * 64;
  const int lrow = lane & 15;
  const int lk = (lane >> 4) * 8;

  f32x4 acc[4][4];
#pragma unroll
  for (int i = 0; i < 4; ++i)
#pragma unroll
    for (int j = 0; j < 4; ++j) acc[i][j] = (f32x4){0.f, 0.f, 0.f, 0.f};

  const int row_s = tid >> 2;         // 0..63
  const int col_s = (tid & 3) * 8;    // 0/8/16/24
  const short* aS = A + (size_t)(tm * 128 + row_s) * K + col_s;
  const short* bS = BT + (size_t)(tn * 128 + row_s) * K + col_s;
  short* AsB = As + wave * 512;       // wave-uniform LDS base
  short* BsB = Bs + wave * 512;

  const int nk = K >> 5;
  for (int kt = 0; kt < nk; ++kt) {
    GLL16(aS, AsB);
    GLL16(aS + (size_t)64 * K, AsB + 2048);
    GLL16(bS, BsB);
    GLL16(bS + (size_t)64 * K, BsB + 2048);
    aS += 32; bS += 32;
    __syncthreads();
    bf16x8 af[4], bfr[4];
#pragma unroll
    for (int i = 0; i < 4; ++i) {
      af[i]  = *(const bf16x8*)(As + (wr + i * 16 + lrow) * 32 + lk);
      bfr[i] = *(const bf16x8*)(Bs + (wc + i * 16 + lrow) * 32 + lk);
    }
#pragma unroll
    for (int i = 0; i < 4; ++i)
#pragma unroll
      for (int j = 0; j < 4; ++j)
        acc[i][j] = __builtin_amdgcn_mfma_f32_16x16x32_bf16(af[i], bfr[j], acc[i][j], 0, 0, 0);
    __syncthreads();
  }

  const int rbase = (lane >> 4) * 4;
#pragma unroll
  for (int j = 0; j < 4; ++j) {
    const int col = tn * 128 + wc + j * 16 + lrow;
    const float bv = bias[col];
#pragma unroll
    for (int i = 0; i < 4; ++i) {
      const int row0 = tm * 128 + wr + i * 16 + rbase;
      f32x4 a = acc[i][j];
      if (MODE == 0) {
        float* C = (float*)Cout;
#pragma unroll
        for (int r = 0; r < 4; ++r) C[(size_t)(row0 + r) * N + col] = a[r] + bv;
      } else if (MODE == 1 || MODE == 2) {
        short* C = (short*)Cout;
#pragma unroll
        for (int r = 0; r < 4; ++r) {
          float v = a[r] + bv;
          if (MODE == 2) v = fmaxf(v, 0.f);
          C[(size_t)(row0 + r) * N + col] = f2bf(v);
        }
      } else {  // MODE 3: Vt[((b*H+h)*KD+kd)*S + s]
        short* C = (short*)Cout;
        const int b = row0 >> 12;
        const int s0 = row0 & (Sn - 1);
        const int h = col >> 8;
        const int kd = col & 255;
        short4v o;
#pragma unroll
        for (int r = 0; r < 4; ++r) o[r] = f2bf(a[r] + bv);
        *(short4v*)(C + (size_t)((b * Hn + h) * KDn + kd) * Sn + s0) = o;
      }
    }
  }
}

// ---------------- sliding-window attention ----------------
// grid (S/128, H, B), 4 waves x 32 queries; online softmax over 32-key chunks
__global__ __launch_bounds__(256, 1)
void attn_win(const short* __restrict__ q, const short* __restrict__ k,
              const short* __restrict__ vt, short* __restrict__ ctx,
              const int* __restrict__ w2p) {
  const int q0 = blockIdx.x * 128;
  const int h = blockIdx.y;
  const int b = blockIdx.z;
  const int lane = threadIdx.x & 63;
  const int wave = threadIdx.x >> 6;
  const int w2 = *w2p;
  const int qw = q0 + wave * 32;
  const int lrow = lane & 15;
  const int lk = (lane >> 4) * 8;
  const int rbase = (lane >> 4) * 4;

  __shared__ __align__(16) short Ps_all[4][1024];
  short* P = Ps_all[wave];

  const short* qbase = q + (size_t)(b * Sn + qw) * NQKVn + h * KDn;
  bf16x8 qf[2][8];
#pragma unroll
  for (int mi = 0; mi < 2; ++mi)
#pragma unroll
    for (int ks = 0; ks < 8; ++ks)
      qf[mi][ks] = *(const bf16x8*)(qbase + (size_t)(mi * 16 + lrow) * NQKVn + ks * 32 + lk);

  f32x4 oacc[2][16];
#pragma unroll
  for (int mi = 0; mi < 2; ++mi)
#pragma unroll
    for (int nc = 0; nc < 16; ++nc) oacc[mi][nc] = (f32x4){0.f, 0.f, 0.f, 0.f};

  float mrun[2][4], lrun[2][4];
#pragma unroll
  for (int mi = 0; mi < 2; ++mi)
#pragma unroll
    for (int r = 0; r < 4; ++r) { mrun[mi][r] = -1e30f; lrun[mi][r] = 0.f; }

  const short* kbase = k + (size_t)(b * Sn) * NQKVn + h * KDn;
  const short* vtb = vt + (size_t)((b * Hn + h) * KDn) * Sn;

  int cstart = q0 - w2; if (cstart < 0) cstart = 0; cstart &= ~31;
  int cend = (q0 + 128 + w2 + 31) & ~31; if (cend > Sn) cend = Sn;

  for (int c0 = cstart; c0 < cend; c0 += 32) {
    f32x4 sf[2][2];
    sf[0][0] = sf[0][1] = sf[1][0] = sf[1][1] = (f32x4){0.f, 0.f, 0.f, 0.f};
#pragma unroll
    for (int ni = 0; ni < 2; ++ni) {
      const short* kc = kbase + (size_t)(c0 + ni * 16 + lrow) * NQKVn + lk;
#pragma unroll
      for (int ks = 0; ks < 8; ++ks) {
        bf16x8 kf = *(const bf16x8*)(kc + ks * 32);
        sf[0][ni] = __builtin_amdgcn_mfma_f32_16x16x32_bf16(qf[0][ks], kf, sf[0][ni], 0, 0, 0);
        sf[1][ni] = __builtin_amdgcn_mfma_f32_16x16x32_bf16(qf[1][ks], kf, sf[1][ni], 0, 0, 0);
      }
    }
    float sc_old[2][4];
#pragma unroll
    for (int mi = 0; mi < 2; ++mi) {
#pragma unroll
      for (int ni = 0; ni < 2; ++ni) {
        const int kk = c0 + ni * 16 + lrow;
#pragma unroll
        for (int r = 0; r < 4; ++r) {
          const int dd = (qw + mi * 16 + rbase + r) - kk;
          const bool val = (dd <= w2) && (dd >= -w2);
          const float s = sf[mi][ni][r] * 0.0625f;
          sf[mi][ni][r] = val ? s : -1e30f;
        }
      }
#pragma unroll
      for (int r = 0; r < 4; ++r) {
        float m = fmaxf(sf[mi][0][r], sf[mi][1][r]);
#pragma unroll
        for (int d = 1; d < 16; d <<= 1) m = fmaxf(m, __shfl_xor(m, d));
        const float mnew = fmaxf(mrun[mi][r], m);
        sc_old[mi][r] = __expf(mrun[mi][r] - mnew);
        mrun[mi][r] = mnew;
        lrun[mi][r] *= sc_old[mi][r];
      }
#pragma unroll
      for (int ni = 0; ni < 2; ++ni)
#pragma unroll
        for (int r = 0; r < 4; ++r) {
          const float sv = sf[mi][ni][r];
          float p = __expf(sv - mrun[mi][r]);
          sf[mi][ni][r] = (sv < -1e29f) ? 0.f : p;
        }
#pragma unroll
      for (int r = 0; r < 4; ++r) {
        float s = sf[mi][0][r] + sf[mi][1][r];
#pragma unroll
        for (int d = 1; d < 16; d <<= 1) s += __shfl_xor(s, d);
        lrun[mi][r] += s;
      }
#pragma unroll
      for (int nc = 0; nc < 16; ++nc)
#pragma unroll
        for (int r = 0; r < 4; ++r) oacc[mi][nc][r] *= sc_old[mi][r];
#pragma unroll
      for (int ni = 0; ni < 2; ++ni)
#pragma unroll
        for (int r = 0; r < 4; ++r)
          P[(mi * 16 + rbase + r) * 32 + ni * 16 + lrow] = f2bf(sf[mi][ni][r]);
    }
    // PV: A = P (32q x 32k), B = Vt rows (kd) x keys
    bf16x8 pa0 = *(const bf16x8*)(P + lrow * 32 + lk);
    bf16x8 pa1 = *(const bf16x8*)(P + (16 + lrow) * 32 + lk);
    const short* vc = vtb + c0 + lk;
#pragma unroll
    for (int nc = 0; nc < 16; ++nc) {
      bf16x8 vf = *(const bf16x8*)(vc + (size_t)(nc * 16 + lrow) * Sn);
      oacc[0][nc] = __builtin_amdgcn_mfma_f32_16x16x32_bf16(pa0, vf, oacc[0][nc], 0, 0, 0);
      oacc[1][nc] = __builtin_amdgcn_mfma_f32_16x16x32_bf16(pa1, vf, oacc[1][nc], 0, 0, 0);
    }
  }
  short* cbase = ctx + (size_t)(b * Sn + qw) * NQKVn + h * KDn;
#pragma unroll
  for (int mi = 0; mi < 2; ++mi) {
    float inv[4];
#pragma unroll
    for (int r = 0; r < 4; ++r) inv[r] = 1.f / lrun[mi][r];
#pragma unroll
    for (int nc = 0; nc < 16; ++nc)
#pragma unroll
      for (int r = 0; r < 4; ++r)
        cbase[(size_t)(mi * 16 + rbase + r) * NQKVn + nc * 16 + lrow] =
            f2bf(oacc[mi][nc][r] * inv[r]);
  }
}

// ---------------- fused residual + LayerNorm ----------------
__global__ __launch_bounds__(256)
void ln_fused(const float* __restrict__ xin, const float* __restrict__ yin,
              const float* __restrict__ g, const float* __restrict__ bb,
              float* __restrict__ of32, short* __restrict__ obf) {
  const int row = blockIdx.x * 4 + (threadIdx.x >> 6);
  const int lane = threadIdx.x & 63;
  const size_t base = (size_t)row * Dn;
  float v[4];
  float sum = 0.f, ssq = 0.f;
#pragma unroll
  for (int i = 0; i < 4; ++i) {
    const int c = lane + 64 * i;
    const float a = xin[base + c] + yin[base + c];
    v[i] = a; sum += a; ssq += a * a;
  }
#pragma unroll
  for (int d = 1; d < 64; d <<= 1) { sum += __shfl_xor(sum, d); ssq += __shfl_xor(ssq, d); }
  const float mu = sum * (1.f / Dn);
  const float var = ssq * (1.f / Dn) - mu * mu;
  const float rs = rsqrtf(var + 1e-3f);
#pragma unroll
  for (int i = 0; i < 4; ++i) {
    const int c = lane + 64 * i;
    const float o = (v[i] - mu) * rs * g[c] + bb[c];
    if (of32) of32[base + c] = o;
    if (obf) obf[base + c] = f2bf(o);
  }
}

extern "C" void kernel_launch(void* const* d_in, const int* in_sizes, int n_in,
                              void* d_out, int out_size, void* d_ws, size_t ws_size,
                              hipStream_t stream) {
  const float* x   = (const float*)d_in[0];
  const int*   w2p = (const int*)d_in[1];
  const float* Wq  = (const float*)d_in[2];
  const float* bq  = (const float*)d_in[3];
  const float* Wk  = (const float*)d_in[4];
  const float* bk  = (const float*)d_in[5];
  const float* Wv  = (const float*)d_in[6];
  const float* bv  = (const float*)d_in[7];
  const float* Wo  = (const float*)d_in[8];
  const float* bo  = (const float*)d_in[9];
  const float* W1  = (const float*)d_in[10];
  const float* b1  = (const float*)d_in[11];
  const float* W2  = (const float*)d_in[12];
  const float* b2  = (const float*)d_in[13];
  const float* g1  = (const float*)d_in[14];
  const float* be1 = (const float*)d_in[15];
  const float* g2  = (const float*)d_in[16];
  const float* be2 = (const float*)d_in[17];
  float* out = (float*)d_out;

  char* ws = (char*)d_ws;
  size_t off = 0;
  auto alloc = [&](size_t bytes) { void* p = ws + off; off += (bytes + 255) & ~(size_t)255; return p; };
  short* xb  = (short*)alloc((size_t)Mn * Dn * 2);
  short* WqT = (short*)alloc((size_t)NQKVn * Dn * 2);
  short* WkT = (short*)alloc((size_t)NQKVn * Dn * 2);
  short* WvT = (short*)alloc((size_t)NQKVn * Dn * 2);
  short* WoT = (short*)alloc((size_t)Dn * NQKVn * 2);
  short* W1T = (short*)alloc((size_t)DFFn * Dn * 2);
  short* W2T = (short*)alloc((size_t)Dn * DFFn * 2);
  short* qb  = (short*)alloc((size_t)Mn * NQKVn * 2);
  short* kb  = (short*)alloc((size_t)Mn * NQKVn * 2);
  short* vtb = (short*)alloc((size_t)Mn * NQKVn * 2);
  float* attn_out = (float*)alloc((size_t)Mn * Dn * 4);
  float* x1 = (float*)alloc((size_t)Mn * Dn * 4);
  // safe aliases (stream-ordered lifetimes; attn reads its own q rows before writing ctx rows)
  short* ctxb = qb;
  short* x1b  = xb;
  short* hb   = kb;
  float* ffn  = attn_out;

  cvt_x<<<dim3(Mn * Dn / 1024), dim3(256), 0, stream>>>(x, xb, Mn * Dn);
  cvt_wT_tiled<<<dim3(Dn / 32, NQKVn / 32), dim3(256), 0, stream>>>(Wq, WqT, Dn, NQKVn);
  cvt_wT_tiled<<<dim3(Dn / 32, NQKVn / 32), dim3(256), 0, stream>>>(Wk, WkT, Dn, NQKVn);
  cvt_wT_tiled<<<dim3(Dn / 32, NQKVn / 32), dim3(256), 0, stream>>>(Wv, WvT, Dn, NQKVn);
  cvt_wT_tiled<<<dim3(NQKVn / 32, Dn / 32), dim3(256), 0, stream>>>(Wo, WoT, NQKVn, Dn);
  cvt_wT_tiled<<<dim3(Dn / 32, DFFn / 32), dim3(256), 0, stream>>>(W1, W1T, Dn, DFFn);
  cvt_wT_tiled<<<dim3(DFFn / 32, Dn / 32), dim3(256), 0, stream>>>(W2, W2T, DFFn, Dn);

  gemm_bt<1><<<dim3(Mn / 128, NQKVn / 128), dim3(256), 0, stream>>>(xb, WqT, bq, qb, NQKVn, Dn);
  gemm_bt<1><<<dim3(Mn / 128, NQKVn / 128), dim3(256), 0, stream>>>(xb, WkT, bk, kb, NQKVn, Dn);
  gemm_bt<3><<<dim3(Mn / 128, NQKVn / 128), dim3(256), 0, stream>>>(xb, WvT, bv, vtb, NQKVn, Dn);

  attn_win<<<dim3(Sn / 128, Hn, Bn), dim3(256), 0, stream>>>(qb, kb, vtb, ctxb, w2p);

  gemm_bt<0><<<dim3(Mn / 128, Dn / 128), dim3(256), 0, stream>>>(ctxb, WoT, bo, attn_out, Dn, NQKVn);
  ln_fused<<<dim3(Mn / 4), dim3(256), 0, stream>>>(x, attn_out, g1, be1, x1, x1b);
  gemm_bt<2><<<dim3(Mn / 128, DFFn / 128), dim3(256), 0, stream>>>(x1b, W1T, b1, hb, DFFn, Dn);
  gemm_bt<0><<<dim3(Mn / 128, Dn / 128), dim3(256), 0, stream>>>(hb, W2T, b2, ffn, Dn, DFFn);
  ln_fused<<<dim3(Mn / 4), dim3(256), 0, stream>>>(x1, ffn, g2, be2, out, (short*)nullptr);
}

// Round 2
// 250.249 us; speedup vs baseline: 1.3010x; 1.3010x over previous
//
#include <hip/hip_runtime.h>
#include <hip/hip_bf16.h>

#define Bn 2
#define Sn 4096
#define Dn 256
#define Hn 8
#define KDn 256
#define DFFn 1024
#define Mn (Bn*Sn)          // 8192
#define NQKVn (Hn*KDn)      // 2048

typedef __attribute__((ext_vector_type(4))) float f32x4;
typedef __attribute__((ext_vector_type(8))) short bf16x8;
typedef __attribute__((ext_vector_type(4))) short short4v;

__device__ __forceinline__ short f2bf(float f) {
  unsigned u = __builtin_bit_cast(unsigned, f);
  unsigned r = u + 0x7fffu + ((u >> 16) & 1u);
  return (short)(r >> 16);
}

#define GLL16(gsrc, ldst) \
  __builtin_amdgcn_global_load_lds((const __attribute__((address_space(1))) void*)(gsrc), \
                                   (__attribute__((address_space(3))) void*)(ldst), 16, 0, 0)

// ---------------- convert x -> bf16 ----------------
__global__ __launch_bounds__(256)
void cvt_x(const float* __restrict__ x, short* __restrict__ xb, int n) {
  int i = (blockIdx.x * 256 + threadIdx.x) * 4;
  if (i < n) {
    float4 v = *(const float4*)(x + i);
    short4v o = { f2bf(v.x), f2bf(v.y), f2bf(v.z), f2bf(v.w) };
    *(short4v*)(xb + i) = o;
  }
}

// ---------------- fused weight transposes: W(K,N) f32 -> WT(N,K) bf16 ----------------
// regions: Wq,Wk,Wv (256x2048, 512 tiles each), Wo (2048x256, 512), W1 (256x1024, 256), W2 (1024x256, 256)
__global__ __launch_bounds__(256)
void cvt_weights(const float* __restrict__ Wq, const float* __restrict__ Wk,
                 const float* __restrict__ Wv, const float* __restrict__ Wo,
                 const float* __restrict__ W1, const float* __restrict__ W2,
                 short* __restrict__ WqT, short* __restrict__ WkT,
                 short* __restrict__ WvT, short* __restrict__ WoT,
                 short* __restrict__ W1T, short* __restrict__ W2T) {
  int t = blockIdx.x;
  const float* W; short* WT; int K, N;
  if      (t < 512)  { W = Wq; WT = WqT; K = 256;  N = 2048; }
  else if (t < 1024) { t -= 512;  W = Wk; WT = WkT; K = 256;  N = 2048; }
  else if (t < 1536) { t -= 1024; W = Wv; WT = WvT; K = 256;  N = 2048; }
  else if (t < 2048) { t -= 1536; W = Wo; WT = WoT; K = 2048; N = 256;  }
  else if (t < 2304) { t -= 2048; W = W1; WT = W1T; K = 256;  N = 1024; }
  else               { t -= 2304; W = W2; WT = W2T; K = 1024; N = 256;  }
  const int ktiles = K >> 5;
  const int k0 = (t % ktiles) * 32, n0 = (t / ktiles) * 32;
  __shared__ short tt[32][33];
  const int tx = threadIdx.x & 31, ty = threadIdx.x >> 5;  // ty 0..7
#pragma unroll
  for (int i = 0; i < 32; i += 8)
    tt[ty + i][tx] = f2bf(W[(size_t)(k0 + ty + i) * N + n0 + tx]);
  __syncthreads();
#pragma unroll
  for (int i = 0; i < 32; i += 8)
    WT[(size_t)(n0 + ty + i) * K + k0 + tx] = tt[tx][ty + i];
}

// ---------------- GEMM 128x128: C = A(MxK,bf16) * BT(NxK,bf16)^T + bias ----------------
// MODE: 0 = f32 out, 1 = bf16 out, 2 = bf16 relu out, 3 = bf16 transposed per-head (Vt), coalesced via LDS
template <int MODE>
__global__ __launch_bounds__(256, 2)
void gemm_bt(const short* __restrict__ A, const short* __restrict__ BT,
             const float* __restrict__ bias, void* __restrict__ Cout,
             int N, int K) {
  __shared__ __align__(16) short smem[(MODE == 3) ? 16640 : 8192];
  short* As = smem;
  short* Bs = smem + 4096;
  const int tid = threadIdx.x;
  const int lane = tid & 63;
  const int wave = tid >> 6;
  const int tm = blockIdx.x;
  const int tn = blockIdx.y;
  const int wr = (wave >> 1) * 64;
  const int wc = (wave & 1) * 64;
  const int lrow = lane & 15;
  const int lk = (lane >> 4) * 8;

  f32x4 acc[4][4];
#pragma unroll
  for (int i = 0; i < 4; ++i)
#pragma unroll
    for (int j = 0; j < 4; ++j) acc[i][j] = (f32x4){0.f, 0.f, 0.f, 0.f};

  const int row_s = tid >> 2;         // 0..63
  const int col_s = (tid & 3) * 8;    // 0/8/16/24
  const short* aS = A + (size_t)(tm * 128 + row_s) * K + col_s;
  const short* bS = BT + (size_t)(tn * 128 + row_s) * K + col_s;
  short* AsB = As + wave * 512;       // wave-uniform LDS base
  short* BsB = Bs + wave * 512;

  const int nk = K >> 5;
  for (int kt = 0; kt < nk; ++kt) {
    GLL16(aS, AsB);
    GLL16(aS + (size_t)64 * K, AsB + 2048);
    GLL16(bS, BsB);
    GLL16(bS + (size_t)64 * K, BsB + 2048);
    aS += 32; bS += 32;
    __syncthreads();
    bf16x8 af[4], bfr[4];
#pragma unroll
    for (int i = 0; i < 4; ++i) {
      af[i]  = *(const bf16x8*)(As + (wr + i * 16 + lrow) * 32 + lk);
      bfr[i] = *(const bf16x8*)(Bs + (wc + i * 16 + lrow) * 32 + lk);
    }
#pragma unroll
    for (int i = 0; i < 4; ++i)
#pragma unroll
      for (int j = 0; j < 4; ++j)
        acc[i][j] = __builtin_amdgcn_mfma_f32_16x16x32_bf16(af[i], bfr[j], acc[i][j], 0, 0, 0);
    __syncthreads();
  }

  const int rbase = (lane >> 4) * 4;
  if (MODE == 3) {
    // stage 128x128 output tile (transposed) in LDS, then coalesced global write.
    __syncthreads();
    short* Ct = smem;  // [128 cols][130 stride]
#pragma unroll
    for (int j = 0; j < 4; ++j) {
      const int colL = wc + j * 16 + lrow;
      const float bv = bias[tn * 128 + colL];
#pragma unroll
      for (int i = 0; i < 4; ++i) {
        const int rowL0 = wr + i * 16 + rbase;
        f32x4 a = acc[i][j];
        short4v o = { f2bf(a[0] + bv), f2bf(a[1] + bv), f2bf(a[2] + bv), f2bf(a[3] + bv) };
        *(short4v*)(&Ct[colL * 130 + rowL0]) = o;
      }
    }
    __syncthreads();
    short* C = (short*)Cout;
    const int kd_l = tid >> 1;             // 0..127
    const int so = (tid & 1) * 64;         // 0/64
    const int col = tn * 128 + kd_l;
    const int h = col >> 8;
    const int kd = col & 255;
    const int row0 = tm * 128;
    const int b = row0 >> 12;
    const int s0 = (row0 & (Sn - 1)) + so;
    short* dst = C + (size_t)((b * Hn + h) * KDn + kd) * Sn + s0;
#pragma unroll
    for (int u = 0; u < 64; u += 8)
      *(bf16x8*)(dst + u) = *(const bf16x8*)(&Ct[kd_l * 130 + so + u]);
    return;
  }

#pragma unroll
  for (int j = 0; j < 4; ++j) {
    const int col = tn * 128 + wc + j * 16 + lrow;
    const float bv = bias[col];
#pragma unroll
    for (int i = 0; i < 4; ++i) {
      const int row0 = tm * 128 + wr + i * 16 + rbase;
      f32x4 a = acc[i][j];
      if (MODE == 0) {
        float* C = (float*)Cout;
#pragma unroll
        for (int r = 0; r < 4; ++r) C[(size_t)(row0 + r) * N + col] = a[r] + bv;
      } else {
        short* C = (short*)Cout;
#pragma unroll
        for (int r = 0; r < 4; ++r) {
          float v = a[r] + bv;
          if (MODE == 2) v = fmaxf(v, 0.f);
          C[(size_t)(row0 + r) * N + col] = f2bf(v);
        }
      }
    }
  }
}

// ---------------- GEMM 64x64 tile (for skinny N=256 GEMMs): f32 out ----------------
__global__ __launch_bounds__(256, 4)
void gemm_bt64(const short* __restrict__ A, const short* __restrict__ BT,
               const float* __restrict__ bias, float* __restrict__ C,
               int N, int K) {
  __shared__ __align__(16) short As[64 * 32];
  __shared__ __align__(16) short Bs[64 * 32];
  const int tid = threadIdx.x;
  const int lane = tid & 63;
  const int wave = tid >> 6;
  const int tm = blockIdx.x;
  const int tn = blockIdx.y;
  const int wr = (wave >> 1) * 32;
  const int wc = (wave & 1) * 32;
  const int lrow = lane & 15;
  const int lk = (lane >> 4) * 8;

  f32x4 acc[2][2];
#pragma unroll
  for (int i = 0; i < 2; ++i)
#pragma unroll
    for (int j = 0; j < 2; ++j) acc[i][j] = (f32x4){0.f, 0.f, 0.f, 0.f};

  const int row_s = tid >> 2;
  const int col_s = (tid & 3) * 8;
  const short* aS = A + (size_t)(tm * 64 + row_s) * K + col_s;
  const short* bS = BT + (size_t)(tn * 64 + row_s) * K + col_s;
  short* AsB = As + wave * 512;
  short* BsB = Bs + wave * 512;

  const int nk = K >> 5;
  for (int kt = 0; kt < nk; ++kt) {
    GLL16(aS, AsB);
    GLL16(bS, BsB);
    aS += 32; bS += 32;
    __syncthreads();
    bf16x8 af[2], bfr[2];
#pragma unroll
    for (int i = 0; i < 2; ++i) {
      af[i]  = *(const bf16x8*)(As + (wr + i * 16 + lrow) * 32 + lk);
      bfr[i] = *(const bf16x8*)(Bs + (wc + i * 16 + lrow) * 32 + lk);
    }
#pragma unroll
    for (int i = 0; i < 2; ++i)
#pragma unroll
      for (int j = 0; j < 2; ++j)
        acc[i][j] = __builtin_amdgcn_mfma_f32_16x16x32_bf16(af[i], bfr[j], acc[i][j], 0, 0, 0);
    __syncthreads();
  }

  const int rbase = (lane >> 4) * 4;
#pragma unroll
  for (int j = 0; j < 2; ++j) {
    const int col = tn * 64 + wc + j * 16 + lrow;
    const float bv = bias[col];
#pragma unroll
    for (int i = 0; i < 2; ++i) {
      const int row0 = tm * 64 + wr + i * 16 + rbase;
      f32x4 a = acc[i][j];
#pragma unroll
      for (int r = 0; r < 4; ++r) C[(size_t)(row0 + r) * N + col] = a[r] + bv;
    }
  }
}

// ---------------- sliding-window attention (unstable-exp softmax) ----------------
// grid (S/128, H, B), 4 waves x 32 queries; per-wave key range; one denom reduce at the end
__global__ __launch_bounds__(256, 2)
void attn_win(const short* __restrict__ q, const short* __restrict__ k,
              const short* __restrict__ vt, short* __restrict__ ctx,
              const int* __restrict__ w2p) {
  const int q0 = blockIdx.x * 128;
  const int h = blockIdx.y;
  const int b = blockIdx.z;
  const int lane = threadIdx.x & 63;
  const int wave = threadIdx.x >> 6;
  const int w2 = *w2p;
  const int qw = q0 + wave * 32;
  const int lrow = lane & 15;
  const int lk = (lane >> 4) * 8;
  const int rbase = (lane >> 4) * 4;

  __shared__ __align__(16) short Ps_all[4][1024];
  short* P = Ps_all[wave];

  const short* qbase = q + (size_t)(b * Sn + qw) * NQKVn + h * KDn;
  bf16x8 qf[2][8];
#pragma unroll
  for (int mi = 0; mi < 2; ++mi)
#pragma unroll
    for (int ks = 0; ks < 8; ++ks)
      qf[mi][ks] = *(const bf16x8*)(qbase + (size_t)(mi * 16 + lrow) * NQKVn + ks * 32 + lk);

  f32x4 oacc[2][16];
#pragma unroll
  for (int mi = 0; mi < 2; ++mi)
#pragma unroll
    for (int nc = 0; nc < 16; ++nc) oacc[mi][nc] = (f32x4){0.f, 0.f, 0.f, 0.f};

  float lsum[2][4];
#pragma unroll
  for (int mi = 0; mi < 2; ++mi)
#pragma unroll
    for (int r = 0; r < 4; ++r) lsum[mi][r] = 0.f;

  const short* kbase = k + (size_t)(b * Sn) * NQKVn + h * KDn;
  const short* vtb = vt + (size_t)((b * Hn + h) * KDn) * Sn;

  // per-wave key range
  int cstart = qw - w2; if (cstart < 0) cstart = 0; cstart &= ~31;
  int cend = qw + 32 + w2; if (cend > Sn) cend = Sn; cend = (cend + 31) & ~31;

  for (int c0 = cstart; c0 < cend; c0 += 32) {
    f32x4 sf[2][2];
    sf[0][0] = sf[0][1] = sf[1][0] = sf[1][1] = (f32x4){0.f, 0.f, 0.f, 0.f};
#pragma unroll
    for (int ni = 0; ni < 2; ++ni) {
      const short* kc = kbase + (size_t)(c0 + ni * 16 + lrow) * NQKVn + lk;
#pragma unroll
      for (int ks = 0; ks < 8; ++ks) {
        bf16x8 kf = *(const bf16x8*)(kc + ks * 32);
        sf[0][ni] = __builtin_amdgcn_mfma_f32_16x16x32_bf16(qf[0][ks], kf, sf[0][ni], 0, 0, 0);
        sf[1][ni] = __builtin_amdgcn_mfma_f32_16x16x32_bf16(qf[1][ks], kf, sf[1][ni], 0, 0, 0);
      }
    }
    // scale + (mask) + exp; accumulate per-lane partial denominator
    const bool full = (c0 >= qw + 31 - w2) && (c0 + 31 <= qw + w2);  // wave-uniform
    if (full) {
#pragma unroll
      for (int mi = 0; mi < 2; ++mi)
#pragma unroll
        for (int ni = 0; ni < 2; ++ni)
#pragma unroll
          for (int r = 0; r < 4; ++r) {
            const float p = __expf(sf[mi][ni][r] * 0.0625f);
            sf[mi][ni][r] = p;
            lsum[mi][r] += p;
          }
    } else {
#pragma unroll
      for (int mi = 0; mi < 2; ++mi)
#pragma unroll
        for (int ni = 0; ni < 2; ++ni) {
          const int kk = c0 + ni * 16 + lrow;
#pragma unroll
          for (int r = 0; r < 4; ++r) {
            const int dd = (qw + mi * 16 + rbase + r) - kk;
            const bool val = (dd <= w2) && (dd >= -w2);
            float p = __expf(sf[mi][ni][r] * 0.0625f);
            p = val ? p : 0.f;
            sf[mi][ni][r] = p;
            lsum[mi][r] += p;
          }
        }
    }
    // stage P (bf16) for the PV A-operand
#pragma unroll
    for (int mi = 0; mi < 2; ++mi)
#pragma unroll
      for (int ni = 0; ni < 2; ++ni)
#pragma unroll
        for (int r = 0; r < 4; ++r)
          P[(mi * 16 + rbase + r) * 32 + ni * 16 + lrow] = f2bf(sf[mi][ni][r]);

    // PV: A = P (32q x 32k), B = Vt rows (kd) x keys
    bf16x8 pa0 = *(const bf16x8*)(P + lrow * 32 + lk);
    bf16x8 pa1 = *(const bf16x8*)(P + (16 + lrow) * 32 + lk);
    const short* vc = vtb + c0 + lk;
#pragma unroll
    for (int nc = 0; nc < 16; ++nc) {
      bf16x8 vf = *(const bf16x8*)(vc + (size_t)(nc * 16 + lrow) * Sn);
      oacc[0][nc] = __builtin_amdgcn_mfma_f32_16x16x32_bf16(pa0, vf, oacc[0][nc], 0, 0, 0);
      oacc[1][nc] = __builtin_amdgcn_mfma_f32_16x16x32_bf16(pa1, vf, oacc[1][nc], 0, 0, 0);
    }
  }

  // one denominator reduce across the 16 key-lanes
#pragma unroll
  for (int mi = 0; mi < 2; ++mi)
#pragma unroll
    for (int r = 0; r < 4; ++r) {
      float s = lsum[mi][r];
#pragma unroll
      for (int d = 1; d < 16; d <<= 1) s += __shfl_xor(s, d);
      lsum[mi][r] = 1.f / s;
    }

  short* cbase = ctx + (size_t)(b * Sn + qw) * NQKVn + h * KDn;
#pragma unroll
  for (int mi = 0; mi < 2; ++mi)
#pragma unroll
    for (int nc = 0; nc < 16; ++nc)
#pragma unroll
      for (int r = 0; r < 4; ++r)
        cbase[(size_t)(mi * 16 + rbase + r) * NQKVn + nc * 16 + lrow] =
            f2bf(oacc[mi][nc][r] * lsum[mi][r]);
}

// ---------------- fused residual + LayerNorm (vectorized) ----------------
__global__ __launch_bounds__(256)
void ln_fused(const float* __restrict__ xin, const float* __restrict__ yin,
              const float* __restrict__ g, const float* __restrict__ bb,
              float* __restrict__ of32, short* __restrict__ obf) {
  const int row = blockIdx.x * 4 + (threadIdx.x >> 6);
  const int lane = threadIdx.x & 63;
  const size_t base = (size_t)row * Dn + lane * 4;
  float4 a = *(const float4*)(xin + base);
  float4 bv = *(const float4*)(yin + base);
  float4 v = { a.x + bv.x, a.y + bv.y, a.z + bv.z, a.w + bv.w };
  float sum = v.x + v.y + v.z + v.w;
  float ssq = v.x * v.x + v.y * v.y + v.z * v.z + v.w * v.w;
#pragma unroll
  for (int d = 1; d < 64; d <<= 1) { sum += __shfl_xor(sum, d); ssq += __shfl_xor(ssq, d); }
  const float mu = sum * (1.f / Dn);
  const float var = ssq * (1.f / Dn) - mu * mu;
  const float rs = rsqrtf(var + 1e-3f);
  float4 gg = *(const float4*)(g + lane * 4);
  float4 bbv = *(const float4*)(bb + lane * 4);
  float4 o = { (v.x - mu) * rs * gg.x + bbv.x, (v.y - mu) * rs * gg.y + bbv.y,
               (v.z - mu) * rs * gg.z + bbv.z, (v.w - mu) * rs * gg.w + bbv.w };
  if (of32) *(float4*)(of32 + base) = o;
  if (obf) {
    short4v ob = { f2bf(o.x), f2bf(o.y), f2bf(o.z), f2bf(o.w) };
    *(short4v*)(obf + base) = ob;
  }
}

extern "C" void kernel_launch(void* const* d_in, const int* in_sizes, int n_in,
                              void* d_out, int out_size, void* d_ws, size_t ws_size,
                              hipStream_t stream) {
  const float* x   = (const float*)d_in[0];
  const int*   w2p = (const int*)d_in[1];
  const float* Wq  = (const float*)d_in[2];
  const float* bq  = (const float*)d_in[3];
  const float* Wk  = (const float*)d_in[4];
  const float* bk  = (const float*)d_in[5];
  const float* Wv  = (const float*)d_in[6];
  const float* bv  = (const float*)d_in[7];
  const float* Wo  = (const float*)d_in[8];
  const float* bo  = (const float*)d_in[9];
  const float* W1  = (const float*)d_in[10];
  const float* b1  = (const float*)d_in[11];
  const float* W2  = (const float*)d_in[12];
  const float* b2  = (const float*)d_in[13];
  const float* g1  = (const float*)d_in[14];
  const float* be1 = (const float*)d_in[15];
  const float* g2  = (const float*)d_in[16];
  const float* be2 = (const float*)d_in[17];
  float* out = (float*)d_out;

  char* ws = (char*)d_ws;
  size_t off = 0;
  auto alloc = [&](size_t bytes) { void* p = ws + off; off += (bytes + 255) & ~(size_t)255; return p; };
  short* xb  = (short*)alloc((size_t)Mn * Dn * 2);
  short* WqT = (short*)alloc((size_t)NQKVn * Dn * 2);
  short* WkT = (short*)alloc((size_t)NQKVn * Dn * 2);
  short* WvT = (short*)alloc((size_t)NQKVn * Dn * 2);
  short* WoT = (short*)alloc((size_t)Dn * NQKVn * 2);
  short* W1T = (short*)alloc((size_t)DFFn * Dn * 2);
  short* W2T = (short*)alloc((size_t)Dn * DFFn * 2);
  short* qb  = (short*)alloc((size_t)Mn * NQKVn * 2);
  short* kb  = (short*)alloc((size_t)Mn * NQKVn * 2);
  short* vtb = (short*)alloc((size_t)Mn * NQKVn * 2);
  float* attn_out = (float*)alloc((size_t)Mn * Dn * 4);
  float* x1 = (float*)alloc((size_t)Mn * Dn * 4);
  // safe aliases (stream-ordered lifetimes; per-(row,col) each attn block reads
  // exactly the q columns it later overwrites with ctx)
  short* ctxb = qb;
  short* x1b  = xb;
  short* hb   = kb;
  float* ffn  = attn_out;

  cvt_x<<<dim3(Mn * Dn / 1024), dim3(256), 0, stream>>>(x, xb, Mn * Dn);
  cvt_weights<<<dim3(2560), dim3(256), 0, stream>>>(Wq, Wk, Wv, Wo, W1, W2,
                                                    WqT, WkT, WvT, WoT, W1T, W2T);

  gemm_bt<1><<<dim3(Mn / 128, NQKVn / 128), dim3(256), 0, stream>>>(xb, WqT, bq, qb, NQKVn, Dn);
  gemm_bt<1><<<dim3(Mn / 128, NQKVn / 128), dim3(256), 0, stream>>>(xb, WkT, bk, kb, NQKVn, Dn);
  gemm_bt<3><<<dim3(Mn / 128, NQKVn / 128), dim3(256), 0, stream>>>(xb, WvT, bv, vtb, NQKVn, Dn);

  attn_win<<<dim3(Sn / 128, Hn, Bn), dim3(256), 0, stream>>>(qb, kb, vtb, ctxb, w2p);

  gemm_bt64<<<dim3(Mn / 64, Dn / 64), dim3(256), 0, stream>>>(ctxb, WoT, bo, attn_out, Dn, NQKVn);
  ln_fused<<<dim3(Mn / 4), dim3(256), 0, stream>>>(x, attn_out, g1, be1, x1, x1b);
  gemm_bt<2><<<dim3(Mn / 128, DFFn / 128), dim3(256), 0, stream>>>(x1b, W1T, b1, hb, DFFn, Dn);
  gemm_bt64<<<dim3(Mn / 64, Dn / 64), dim3(256), 0, stream>>>(hb, W2T, b2, ffn, Dn, DFFn);
  ln_fused<<<dim3(Mn / 4), dim3(256), 0, stream>>>(x1, ffn, g2, be2, out, (short*)nullptr);
}

// Round 3
// 202.058 us; speedup vs baseline: 1.6113x; 1.2385x over previous
//
#include <hip/hip_runtime.h>
#include <hip/hip_bf16.h>

#define Bn 2
#define Sn 4096
#define Dn 256
#define Hn 8
#define KDn 256
#define DFFn 1024
#define Mn (Bn*Sn)          // 8192
#define NQKVn (Hn*KDn)      // 2048

typedef __attribute__((ext_vector_type(4))) float f32x4;
typedef __attribute__((ext_vector_type(8))) short bf16x8;
typedef __attribute__((ext_vector_type(4))) short short4v;

__device__ __forceinline__ short f2bf(float f) {
  unsigned u = __builtin_bit_cast(unsigned, f);
  unsigned r = u + 0x7fffu + ((u >> 16) & 1u);
  return (short)(r >> 16);
}

#define GLL16(gsrc, ldst) \
  __builtin_amdgcn_global_load_lds((const __attribute__((address_space(1))) void*)(gsrc), \
                                   (__attribute__((address_space(3))) void*)(ldst), 16, 0, 0)

// ---------------- convert x -> bf16 ----------------
__global__ __launch_bounds__(256)
void cvt_x(const float* __restrict__ x, short* __restrict__ xb, int n) {
  int i = (blockIdx.x * 256 + threadIdx.x) * 4;
  if (i < n) {
    float4 v = *(const float4*)(x + i);
    short4v o = { f2bf(v.x), f2bf(v.y), f2bf(v.z), f2bf(v.w) };
    *(short4v*)(xb + i) = o;
  }
}

// ---------------- bias concat for fused QKV ----------------
__global__ __launch_bounds__(256)
void concat_bias(const float* __restrict__ bq, const float* __restrict__ bk,
                 const float* __restrict__ bv, float* __restrict__ o) {
  int i = blockIdx.x * 256 + threadIdx.x;  // 6144
  o[i] = (i < 2048) ? bq[i] : (i < 4096 ? bk[i - 2048] : bv[i - 4096]);
}

// ---------------- fused weight transposes: W(K,N) f32 -> WT(N,K) bf16 ----------------
__global__ __launch_bounds__(256)
void cvt_weights(const float* __restrict__ Wq, const float* __restrict__ Wk,
                 const float* __restrict__ Wv, const float* __restrict__ Wo,
                 const float* __restrict__ W1, const float* __restrict__ W2,
                 short* __restrict__ WqT, short* __restrict__ WkT,
                 short* __restrict__ WvT, short* __restrict__ WoT,
                 short* __restrict__ W1T, short* __restrict__ W2T) {
  int t = blockIdx.x;
  const float* W; short* WT; int K, N;
  if      (t < 512)  { W = Wq; WT = WqT; K = 256;  N = 2048; }
  else if (t < 1024) { t -= 512;  W = Wk; WT = WkT; K = 256;  N = 2048; }
  else if (t < 1536) { t -= 1024; W = Wv; WT = WvT; K = 256;  N = 2048; }
  else if (t < 2048) { t -= 1536; W = Wo; WT = WoT; K = 2048; N = 256;  }
  else if (t < 2304) { t -= 2048; W = W1; WT = W1T; K = 256;  N = 1024; }
  else               { t -= 2304; W = W2; WT = W2T; K = 1024; N = 256;  }
  const int ktiles = K >> 5;
  const int k0 = (t % ktiles) * 32, n0 = (t / ktiles) * 32;
  __shared__ short tt[32][33];
  const int tx = threadIdx.x & 31, ty = threadIdx.x >> 5;
#pragma unroll
  for (int i = 0; i < 32; i += 8)
    tt[ty + i][tx] = f2bf(W[(size_t)(k0 + ty + i) * N + n0 + tx]);
  __syncthreads();
#pragma unroll
  for (int i = 0; i < 32; i += 8)
    WT[(size_t)(n0 + ty + i) * K + k0 + tx] = tt[tx][ty + i];
}

// ---------------- fused QKV GEMM: C(M x 6144) = A * WqkvT^T + bias ----------------
// cols 0..2047 -> Q (bf16), 2048..4095 -> K (bf16, pre-scaled 1/16), 4096..6143 -> Vt (transposed per head)
__global__ __launch_bounds__(256, 2)
void gemm_qkv(const short* __restrict__ A, const short* __restrict__ BT,
              const float* __restrict__ bias, short* __restrict__ Qo,
              short* __restrict__ Ko, short* __restrict__ Vto) {
  __shared__ __align__(16) short smem[16640];
  short* As = smem;
  short* Bs = smem + 4096;
  const int tid = threadIdx.x;
  const int lane = tid & 63;
  const int wave = tid >> 6;
  const int tn = blockIdx.x;   // 0..47 (tn-fastest: B stays L2-resident)
  const int tm = blockIdx.y;   // 0..63
  const int wr = (wave >> 1) * 64;
  const int wc = (wave & 1) * 64;
  const int lrow = lane & 15;
  const int lk = (lane >> 4) * 8;
  const int K = 256;

  f32x4 acc[4][4];
#pragma unroll
  for (int i = 0; i < 4; ++i)
#pragma unroll
    for (int j = 0; j < 4; ++j) acc[i][j] = (f32x4){0.f, 0.f, 0.f, 0.f};

  const int row_s = tid >> 2;
  const int col_s = (tid & 3) * 8;
  const short* aS = A + (size_t)(tm * 128 + row_s) * K + col_s;
  const short* bS = BT + (size_t)(tn * 128 + row_s) * K + col_s;
  short* AsB = As + wave * 512;
  short* BsB = Bs + wave * 512;

  for (int kt = 0; kt < 8; ++kt) {
    GLL16(aS, AsB);
    GLL16(aS + (size_t)64 * K, AsB + 2048);
    GLL16(bS, BsB);
    GLL16(bS + (size_t)64 * K, BsB + 2048);
    aS += 32; bS += 32;
    __syncthreads();
    bf16x8 af[4], bfr[4];
#pragma unroll
    for (int i = 0; i < 4; ++i) {
      af[i]  = *(const bf16x8*)(As + (wr + i * 16 + lrow) * 32 + lk);
      bfr[i] = *(const bf16x8*)(Bs + (wc + i * 16 + lrow) * 32 + lk);
    }
#pragma unroll
    for (int i = 0; i < 4; ++i)
#pragma unroll
      for (int j = 0; j < 4; ++j)
        acc[i][j] = __builtin_amdgcn_mfma_f32_16x16x32_bf16(af[i], bfr[j], acc[i][j], 0, 0, 0);
    __syncthreads();
  }

  const int rbase = (lane >> 4) * 4;
  if (tn < 32) {
    short* C = (tn < 16) ? Qo : Ko;
    const float sc = (tn < 16) ? 1.f : 0.0625f;   // pre-scale K by 1/sqrt(KD)
    const int cb = (tn & 15) * 128;
#pragma unroll
    for (int j = 0; j < 4; ++j) {
      const int cj = wc + j * 16 + lrow;
      const float bv = bias[tn * 128 + cj];
      const int cl = cb + cj;
#pragma unroll
      for (int i = 0; i < 4; ++i) {
        const int row0 = tm * 128 + wr + i * 16 + rbase;
        f32x4 a = acc[i][j];
#pragma unroll
        for (int r = 0; r < 4; ++r)
          C[(size_t)(row0 + r) * NQKVn + cl] = f2bf((a[r] + bv) * sc);
      }
    }
  } else {
    // V: stage transposed tile in LDS, write Vt coalesced
    __syncthreads();
    short* Ct = smem;  // [128 cols][130]
#pragma unroll
    for (int j = 0; j < 4; ++j) {
      const int colL = wc + j * 16 + lrow;
      const float bv = bias[tn * 128 + colL];
#pragma unroll
      for (int i = 0; i < 4; ++i) {
        const int rowL0 = wr + i * 16 + rbase;
        f32x4 a = acc[i][j];
        short4v o = { f2bf(a[0] + bv), f2bf(a[1] + bv), f2bf(a[2] + bv), f2bf(a[3] + bv) };
        *(short4v*)(&Ct[colL * 130 + rowL0]) = o;
      }
    }
    __syncthreads();
    const int kd_l = tid >> 1;
    const int so = (tid & 1) * 64;
    const int cl = (tn - 32) * 128 + kd_l;
    const int hh = cl >> 8;
    const int kd = cl & 255;
    const int row0 = tm * 128;
    const int bb = row0 >> 12;
    const int s0 = (row0 & (Sn - 1)) + so;
    short* dst = Vto + (size_t)((bb * Hn + hh) * KDn + kd) * Sn + s0;
#pragma unroll
    for (int u = 0; u < 64; u += 8)
      *(bf16x8*)(dst + u) = *(const bf16x8*)(&Ct[kd_l * 130 + so + u]);
  }
}

// ---------------- GEMM 128x128 (FFN1): bf16 relu out, tn-fastest grid ----------------
__global__ __launch_bounds__(256, 2)
void gemm_ffn1(const short* __restrict__ A, const short* __restrict__ BT,
               const float* __restrict__ bias, short* __restrict__ C,
               int N, int K) {
  __shared__ __align__(16) short As[128 * 32];
  __shared__ __align__(16) short Bs[128 * 32];
  const int tid = threadIdx.x;
  const int lane = tid & 63;
  const int wave = tid >> 6;
  const int tn = blockIdx.x;
  const int tm = blockIdx.y;
  const int wr = (wave >> 1) * 64;
  const int wc = (wave & 1) * 64;
  const int lrow = lane & 15;
  const int lk = (lane >> 4) * 8;

  f32x4 acc[4][4];
#pragma unroll
  for (int i = 0; i < 4; ++i)
#pragma unroll
    for (int j = 0; j < 4; ++j) acc[i][j] = (f32x4){0.f, 0.f, 0.f, 0.f};

  const int row_s = tid >> 2;
  const int col_s = (tid & 3) * 8;
  const short* aS = A + (size_t)(tm * 128 + row_s) * K + col_s;
  const short* bS = BT + (size_t)(tn * 128 + row_s) * K + col_s;
  short* AsB = As + wave * 512;
  short* BsB = Bs + wave * 512;

  const int nk = K >> 5;
  for (int kt = 0; kt < nk; ++kt) {
    GLL16(aS, AsB);
    GLL16(aS + (size_t)64 * K, AsB + 2048);
    GLL16(bS, BsB);
    GLL16(bS + (size_t)64 * K, BsB + 2048);
    aS += 32; bS += 32;
    __syncthreads();
    bf16x8 af[4], bfr[4];
#pragma unroll
    for (int i = 0; i < 4; ++i) {
      af[i]  = *(const bf16x8*)(As + (wr + i * 16 + lrow) * 32 + lk);
      bfr[i] = *(const bf16x8*)(Bs + (wc + i * 16 + lrow) * 32 + lk);
    }
#pragma unroll
    for (int i = 0; i < 4; ++i)
#pragma unroll
      for (int j = 0; j < 4; ++j)
        acc[i][j] = __builtin_amdgcn_mfma_f32_16x16x32_bf16(af[i], bfr[j], acc[i][j], 0, 0, 0);
    __syncthreads();
  }

  const int rbase = (lane >> 4) * 4;
#pragma unroll
  for (int j = 0; j < 4; ++j) {
    const int col = tn * 128 + wc + j * 16 + lrow;
    const float bv = bias[col];
#pragma unroll
    for (int i = 0; i < 4; ++i) {
      const int row0 = tm * 128 + wr + i * 16 + rbase;
      f32x4 a = acc[i][j];
#pragma unroll
      for (int r = 0; r < 4; ++r)
        C[(size_t)(row0 + r) * N + col] = f2bf(fmaxf(a[r] + bv, 0.f));
    }
  }
}

// ---------------- GEMM 64x64 tile (skinny N=256): f32 out, tn-fastest grid ----------------
__global__ __launch_bounds__(256, 4)
void gemm_bt64(const short* __restrict__ A, const short* __restrict__ BT,
               const float* __restrict__ bias, float* __restrict__ C,
               int N, int K) {
  __shared__ __align__(16) short As[64 * 32];
  __shared__ __align__(16) short Bs[64 * 32];
  const int tid = threadIdx.x;
  const int lane = tid & 63;
  const int wave = tid >> 6;
  const int tn = blockIdx.x;
  const int tm = blockIdx.y;
  const int wr = (wave >> 1) * 32;
  const int wc = (wave & 1) * 32;
  const int lrow = lane & 15;
  const int lk = (lane >> 4) * 8;

  f32x4 acc[2][2];
#pragma unroll
  for (int i = 0; i < 2; ++i)
#pragma unroll
    for (int j = 0; j < 2; ++j) acc[i][j] = (f32x4){0.f, 0.f, 0.f, 0.f};

  const int row_s = tid >> 2;
  const int col_s = (tid & 3) * 8;
  const short* aS = A + (size_t)(tm * 64 + row_s) * K + col_s;
  const short* bS = BT + (size_t)(tn * 64 + row_s) * K + col_s;
  short* AsB = As + wave * 512;
  short* BsB = Bs + wave * 512;

  const int nk = K >> 5;
  for (int kt = 0; kt < nk; ++kt) {
    GLL16(aS, AsB);
    GLL16(bS, BsB);
    aS += 32; bS += 32;
    __syncthreads();
    bf16x8 af[2], bfr[2];
#pragma unroll
    for (int i = 0; i < 2; ++i) {
      af[i]  = *(const bf16x8*)(As + (wr + i * 16 + lrow) * 32 + lk);
      bfr[i] = *(const bf16x8*)(Bs + (wc + i * 16 + lrow) * 32 + lk);
    }
#pragma unroll
    for (int i = 0; i < 2; ++i)
#pragma unroll
      for (int j = 0; j < 2; ++j)
        acc[i][j] = __builtin_amdgcn_mfma_f32_16x16x32_bf16(af[i], bfr[j], acc[i][j], 0, 0, 0);
    __syncthreads();
  }

  const int rbase = (lane >> 4) * 4;
#pragma unroll
  for (int j = 0; j < 2; ++j) {
    const int col = tn * 64 + wc + j * 16 + lrow;
    const float bv = bias[col];
#pragma unroll
    for (int i = 0; i < 2; ++i) {
      const int row0 = tm * 64 + wr + i * 16 + rbase;
      f32x4 a = acc[i][j];
#pragma unroll
      for (int r = 0; r < 4; ++r) C[(size_t)(row0 + r) * N + col] = a[r] + bv;
    }
  }
}

// ---------------- sliding-window attention, LDS-staged K/V ----------------
// grid (S/256, H, B), 512 threads = 8 waves x 32 queries. Per-chunk (32 keys):
// stage K(32x256) + Vt(256x32) into LDS once per block (double-buffered,
// pre-swizzled global source -> linear LDS, XOR-swizzled ds_read_b128).
__global__ __launch_bounds__(512, 2)
void attn_win(const short* __restrict__ q, const short* __restrict__ k,
              const short* __restrict__ vt, short* __restrict__ ctx,
              const int* __restrict__ w2p) {
  const int q0 = blockIdx.x * 256;
  const int h = blockIdx.y;
  const int b = blockIdx.z;
  const int tid = threadIdx.x;
  const int lane = tid & 63;
  const int wave = tid >> 6;
  const int w2 = *w2p;
  const int qw = q0 + wave * 32;
  const int lrow = lane & 15;
  const int lk = (lane >> 4) * 8;
  const int lk2 = lk * 2;
  const int rbase = (lane >> 4) * 4;

  __shared__ __align__(16) short Ks[2][8192];   // 32 keys x 256 kd (512B rows, xor (r&7)<<4)
  __shared__ __align__(16) short Vs[2][8192];   // 256 kd x 32 keys (64B rows, xor (r&3)<<4)
  __shared__ __align__(16) short Ps[8][1024];
  short* P = Ps[wave];

  const short* qbase = q + (size_t)(b * Sn + qw) * NQKVn + h * KDn;
  bf16x8 qf[2][8];
#pragma unroll
  for (int mi = 0; mi < 2; ++mi)
#pragma unroll
    for (int ks = 0; ks < 8; ++ks)
      qf[mi][ks] = *(const bf16x8*)(qbase + (size_t)(mi * 16 + lrow) * NQKVn + ks * 32 + lk);

  f32x4 oacc[2][16];
#pragma unroll
  for (int mi = 0; mi < 2; ++mi)
#pragma unroll
    for (int nc = 0; nc < 16; ++nc) oacc[mi][nc] = (f32x4){0.f, 0.f, 0.f, 0.f};

  float lsum[2][4];
#pragma unroll
  for (int mi = 0; mi < 2; ++mi)
#pragma unroll
    for (int r = 0; r < 4; ++r) lsum[mi][r] = 0.f;

  const short* kbase = k + (size_t)(b * Sn) * NQKVn + h * KDn;
  const short* vtb = vt + (size_t)((b * Hn + h) * KDn) * Sn;

  int bstart = q0 - w2; if (bstart < 0) bstart = 0; bstart &= ~31;
  int bend = q0 + 256 + w2; if (bend > Sn) bend = Sn; bend = (bend + 31) & ~31;
  int wlo = qw - w2; if (wlo < 0) wlo = 0; wlo &= ~31;
  int whi = qw + 32 + w2; if (whi > Sn) whi = Sn;

  auto stage = [&](int c0, int bf) {
#pragma unroll
    for (int e = 0; e < 2; ++e) {   // K chunk: 2 x 8KB
      const int o = e * 8192 + tid * 16;
      const int row = o >> 9;
      const int cc = (o & 511) ^ ((row & 7) << 4);
      GLL16(kbase + (size_t)(c0 + row) * NQKVn + (cc >> 1),
            (char*)Ks[bf] + e * 8192 + wave * 1024);
    }
#pragma unroll
    for (int e = 0; e < 2; ++e) {   // V chunk: 2 x 8KB
      const int o = e * 8192 + tid * 16;
      const int row = o >> 6;
      const int cc = (o & 63) ^ ((row & 3) << 4);
      GLL16(vtb + (size_t)row * Sn + c0 + (cc >> 1),
            (char*)Vs[bf] + e * 8192 + wave * 1024);
    }
  };

  const int nch = (bend - bstart) >> 5;
  stage(bstart, 0);
  __syncthreads();

  for (int i = 0; i < nch; ++i) {
    const int c0 = bstart + i * 32;
    const int cur = i & 1;
    if (i + 1 < nch) stage(c0 + 32, cur ^ 1);   // issue next-tile loads, in flight during compute
    if (c0 >= wlo && c0 < whi) {                // wave-uniform skip
      const char* Kc = (const char*)Ks[cur];
      const int x0 = (lrow & 7) << 4;
      f32x4 sf[2][2];
      sf[0][0] = sf[0][1] = sf[1][0] = sf[1][1] = (f32x4){0.f, 0.f, 0.f, 0.f};
#pragma unroll
      for (int ks = 0; ks < 8; ++ks) {
        const int cb = (lk2 + ks * 64) ^ x0;
        bf16x8 kf0 = *(const bf16x8*)(Kc + lrow * 512 + cb);
        bf16x8 kf1 = *(const bf16x8*)(Kc + (16 + lrow) * 512 + cb);
        sf[0][0] = __builtin_amdgcn_mfma_f32_16x16x32_bf16(qf[0][ks], kf0, sf[0][0], 0, 0, 0);
        sf[0][1] = __builtin_amdgcn_mfma_f32_16x16x32_bf16(qf[0][ks], kf1, sf[0][1], 0, 0, 0);
        sf[1][0] = __builtin_amdgcn_mfma_f32_16x16x32_bf16(qf[1][ks], kf0, sf[1][0], 0, 0, 0);
        sf[1][1] = __builtin_amdgcn_mfma_f32_16x16x32_bf16(qf[1][ks], kf1, sf[1][1], 0, 0, 0);
      }
      const bool full = (c0 >= qw + 31 - w2) && (c0 + 31 <= qw + w2);
      if (full) {
#pragma unroll
        for (int mi = 0; mi < 2; ++mi)
#pragma unroll
          for (int ni = 0; ni < 2; ++ni)
#pragma unroll
            for (int r = 0; r < 4; ++r) {
              const float p = __expf(sf[mi][ni][r]);   // K pre-scaled by 1/16
              sf[mi][ni][r] = p;
              lsum[mi][r] += p;
            }
      } else {
#pragma unroll
        for (int mi = 0; mi < 2; ++mi)
#pragma unroll
          for (int ni = 0; ni < 2; ++ni) {
            const int kk = c0 + ni * 16 + lrow;
#pragma unroll
            for (int r = 0; r < 4; ++r) {
              const int dd = (qw + mi * 16 + rbase + r) - kk;
              const bool val = (dd <= w2) && (dd >= -w2);
              float p = __expf(sf[mi][ni][r]);
              p = val ? p : 0.f;
              sf[mi][ni][r] = p;
              lsum[mi][r] += p;
            }
          }
      }
#pragma unroll
      for (int mi = 0; mi < 2; ++mi)
#pragma unroll
        for (int ni = 0; ni < 2; ++ni)
#pragma unroll
          for (int r = 0; r < 4; ++r)
            P[(mi * 16 + rbase + r) * 32 + ni * 16 + lrow] = f2bf(sf[mi][ni][r]);

      bf16x8 pa0 = *(const bf16x8*)(P + lrow * 32 + lk);
      bf16x8 pa1 = *(const bf16x8*)(P + (16 + lrow) * 32 + lk);
      const char* Vc = (const char*)Vs[cur] + lrow * 64 + (lk2 ^ ((lrow & 3) << 4));
#pragma unroll
      for (int nc = 0; nc < 16; ++nc) {
        bf16x8 vf = *(const bf16x8*)(Vc + nc * 1024);
        oacc[0][nc] = __builtin_amdgcn_mfma_f32_16x16x32_bf16(pa0, vf, oacc[0][nc], 0, 0, 0);
        oacc[1][nc] = __builtin_amdgcn_mfma_f32_16x16x32_bf16(pa1, vf, oacc[1][nc], 0, 0, 0);
      }
    }
    __syncthreads();   // next buffer staged; everyone done reading cur
  }

#pragma unroll
  for (int mi = 0; mi < 2; ++mi)
#pragma unroll
    for (int r = 0; r < 4; ++r) {
      float s = lsum[mi][r];
#pragma unroll
      for (int d = 1; d < 16; d <<= 1) s += __shfl_xor(s, d);
      lsum[mi][r] = 1.f / s;
    }

  short* cbase = ctx + (size_t)(b * Sn + qw) * NQKVn + h * KDn;
#pragma unroll
  for (int mi = 0; mi < 2; ++mi)
#pragma unroll
    for (int nc = 0; nc < 16; ++nc)
#pragma unroll
      for (int r = 0; r < 4; ++r)
        cbase[(size_t)(mi * 16 + rbase + r) * NQKVn + nc * 16 + lrow] =
            f2bf(oacc[mi][nc][r] * lsum[mi][r]);
}

// ---------------- fused residual + LayerNorm (vectorized) ----------------
__global__ __launch_bounds__(256)
void ln_fused(const float* __restrict__ xin, const float* __restrict__ yin,
              const float* __restrict__ g, const float* __restrict__ bb,
              float* __restrict__ of32, short* __restrict__ obf) {
  const int row = blockIdx.x * 4 + (threadIdx.x >> 6);
  const int lane = threadIdx.x & 63;
  const size_t base = (size_t)row * Dn + lane * 4;
  float4 a = *(const float4*)(xin + base);
  float4 bv = *(const float4*)(yin + base);
  float4 v = { a.x + bv.x, a.y + bv.y, a.z + bv.z, a.w + bv.w };
  float sum = v.x + v.y + v.z + v.w;
  float ssq = v.x * v.x + v.y * v.y + v.z * v.z + v.w * v.w;
#pragma unroll
  for (int d = 1; d < 64; d <<= 1) { sum += __shfl_xor(sum, d); ssq += __shfl_xor(ssq, d); }
  const float mu = sum * (1.f / Dn);
  const float var = ssq * (1.f / Dn) - mu * mu;
  const float rs = rsqrtf(var + 1e-3f);
  float4 gg = *(const float4*)(g + lane * 4);
  float4 bbv = *(const float4*)(bb + lane * 4);
  float4 o = { (v.x - mu) * rs * gg.x + bbv.x, (v.y - mu) * rs * gg.y + bbv.y,
               (v.z - mu) * rs * gg.z + bbv.z, (v.w - mu) * rs * gg.w + bbv.w };
  if (of32) *(float4*)(of32 + base) = o;
  if (obf) {
    short4v ob = { f2bf(o.x), f2bf(o.y), f2bf(o.z), f2bf(o.w) };
    *(short4v*)(obf + base) = ob;
  }
}

extern "C" void kernel_launch(void* const* d_in, const int* in_sizes, int n_in,
                              void* d_out, int out_size, void* d_ws, size_t ws_size,
                              hipStream_t stream) {
  const float* x   = (const float*)d_in[0];
  const int*   w2p = (const int*)d_in[1];
  const float* Wq  = (const float*)d_in[2];
  const float* bq  = (const float*)d_in[3];
  const float* Wk  = (const float*)d_in[4];
  const float* bk  = (const float*)d_in[5];
  const float* Wv  = (const float*)d_in[6];
  const float* bv  = (const float*)d_in[7];
  const float* Wo  = (const float*)d_in[8];
  const float* bo  = (const float*)d_in[9];
  const float* W1  = (const float*)d_in[10];
  const float* b1  = (const float*)d_in[11];
  const float* W2  = (const float*)d_in[12];
  const float* b2  = (const float*)d_in[13];
  const float* g1  = (const float*)d_in[14];
  const float* be1 = (const float*)d_in[15];
  const float* g2  = (const float*)d_in[16];
  const float* be2 = (const float*)d_in[17];
  float* out = (float*)d_out;

  char* ws = (char*)d_ws;
  size_t off = 0;
  auto alloc = [&](size_t bytes) { void* p = ws + off; off += (bytes + 255) & ~(size_t)255; return p; };
  short* xb    = (short*)alloc((size_t)Mn * Dn * 2);
  short* WqkvT = (short*)alloc((size_t)3 * NQKVn * Dn * 2);   // [6144][256]
  float* bqkv  = (float*)alloc((size_t)3 * NQKVn * 4);
  short* WoT   = (short*)alloc((size_t)Dn * NQKVn * 2);
  short* W1T   = (short*)alloc((size_t)DFFn * Dn * 2);
  short* W2T   = (short*)alloc((size_t)Dn * DFFn * 2);
  short* qb    = (short*)alloc((size_t)Mn * NQKVn * 2);
  short* kb    = (short*)alloc((size_t)Mn * NQKVn * 2);
  short* vtb   = (short*)alloc((size_t)Mn * NQKVn * 2);
  float* attn_out = (float*)alloc((size_t)Mn * Dn * 4);
  float* x1    = (float*)alloc((size_t)Mn * Dn * 4);
  // stream-ordered safe aliases
  short* ctxb = qb;
  short* x1b  = xb;
  short* hb   = kb;
  float* ffn  = attn_out;

  cvt_x<<<dim3(Mn * Dn / 1024), dim3(256), 0, stream>>>(x, xb, Mn * Dn);
  cvt_weights<<<dim3(2560), dim3(256), 0, stream>>>(
      Wq, Wk, Wv, Wo, W1, W2,
      WqkvT, WqkvT + (size_t)NQKVn * Dn, WqkvT + (size_t)2 * NQKVn * Dn,
      WoT, W1T, W2T);
  concat_bias<<<dim3(24), dim3(256), 0, stream>>>(bq, bk, bv, bqkv);

  gemm_qkv<<<dim3(48, 64), dim3(256), 0, stream>>>(xb, WqkvT, bqkv, qb, kb, vtb);

  attn_win<<<dim3(Sn / 256, Hn, Bn), dim3(512), 0, stream>>>(qb, kb, vtb, ctxb, w2p);

  gemm_bt64<<<dim3(Dn / 64, Mn / 64), dim3(256), 0, stream>>>(ctxb, WoT, bo, attn_out, Dn, NQKVn);
  ln_fused<<<dim3(Mn / 4), dim3(256), 0, stream>>>(x, attn_out, g1, be1, x1, x1b);
  gemm_ffn1<<<dim3(DFFn / 128, Mn / 128), dim3(256), 0, stream>>>(x1b, W1T, b1, hb, DFFn, Dn);
  gemm_bt64<<<dim3(Dn / 64, Mn / 64), dim3(256), 0, stream>>>(hb, W2T, b2, ffn, Dn, DFFn);
  ln_fused<<<dim3(Mn / 4), dim3(256), 0, stream>>>(x1, ffn, g2, be2, out, (short*)nullptr);
}

// Round 4
// 185.002 us; speedup vs baseline: 1.7599x; 1.0922x over previous
//
#include <hip/hip_runtime.h>
#include <hip/hip_bf16.h>

#define Bn 2
#define Sn 4096
#define Dn 256
#define Hn 8
#define KDn 256
#define DFFn 1024
#define Mn (Bn*Sn)          // 8192
#define NQKVn (Hn*KDn)      // 2048

typedef __attribute__((ext_vector_type(4))) float f32x4;
typedef __attribute__((ext_vector_type(8))) short bf16x8;
typedef __attribute__((ext_vector_type(4))) short short4v;

__device__ __forceinline__ short f2bf(float f) {
  unsigned u = __builtin_bit_cast(unsigned, f);
  unsigned r = u + 0x7fffu + ((u >> 16) & 1u);
  return (short)(r >> 16);
}

#define GLL16(gsrc, ldst) \
  __builtin_amdgcn_global_load_lds((const __attribute__((address_space(1))) void*)(gsrc), \
                                   (__attribute__((address_space(3))) void*)(ldst), 16, 0, 0)

// ---------------- convert x -> bf16 ----------------
__global__ __launch_bounds__(256)
void cvt_x(const float* __restrict__ x, short* __restrict__ xb, int n) {
  int i = (blockIdx.x * 256 + threadIdx.x) * 4;
  if (i < n) {
    float4 v = *(const float4*)(x + i);
    short4v o = { f2bf(v.x), f2bf(v.y), f2bf(v.z), f2bf(v.w) };
    *(short4v*)(xb + i) = o;
  }
}

// ---------------- bias concat for fused QKV ----------------
__global__ __launch_bounds__(256)
void concat_bias(const float* __restrict__ bq, const float* __restrict__ bk,
                 const float* __restrict__ bv, float* __restrict__ o) {
  int i = blockIdx.x * 256 + threadIdx.x;  // 6144
  o[i] = (i < 2048) ? bq[i] : (i < 4096 ? bk[i - 2048] : bv[i - 4096]);
}

// ---------------- fused weight transposes: W(K,N) f32 -> WT(N,K) bf16 ----------------
__global__ __launch_bounds__(256)
void cvt_weights(const float* __restrict__ Wq, const float* __restrict__ Wk,
                 const float* __restrict__ Wv, const float* __restrict__ Wo,
                 const float* __restrict__ W1, const float* __restrict__ W2,
                 short* __restrict__ WqT, short* __restrict__ WkT,
                 short* __restrict__ WvT, short* __restrict__ WoT,
                 short* __restrict__ W1T, short* __restrict__ W2T) {
  int t = blockIdx.x;
  const float* W; short* WT; int K, N;
  if      (t < 512)  { W = Wq; WT = WqT; K = 256;  N = 2048; }
  else if (t < 1024) { t -= 512;  W = Wk; WT = WkT; K = 256;  N = 2048; }
  else if (t < 1536) { t -= 1024; W = Wv; WT = WvT; K = 256;  N = 2048; }
  else if (t < 2048) { t -= 1536; W = Wo; WT = WoT; K = 2048; N = 256;  }
  else if (t < 2304) { t -= 2048; W = W1; WT = W1T; K = 256;  N = 1024; }
  else               { t -= 2304; W = W2; WT = W2T; K = 1024; N = 256;  }
  const int ktiles = K >> 5;
  const int k0 = (t % ktiles) * 32, n0 = (t / ktiles) * 32;
  __shared__ short tt[32][33];
  const int tx = threadIdx.x & 31, ty = threadIdx.x >> 5;
#pragma unroll
  for (int i = 0; i < 32; i += 8)
    tt[ty + i][tx] = f2bf(W[(size_t)(k0 + ty + i) * N + n0 + tx]);
  __syncthreads();
#pragma unroll
  for (int i = 0; i < 32; i += 8)
    WT[(size_t)(n0 + ty + i) * K + k0 + tx] = tt[tx][ty + i];
}

// ---------------- fused QKV GEMM: C(M x 6144) = A * WqkvT^T + bias ----------------
// cols 0..2047 -> Q (bf16), 2048..4095 -> K (bf16, pre-scaled 1/16), 4096..6143 -> Vt (transposed per head)
__global__ __launch_bounds__(256, 2)
void gemm_qkv(const short* __restrict__ A, const short* __restrict__ BT,
              const float* __restrict__ bias, short* __restrict__ Qo,
              short* __restrict__ Ko, short* __restrict__ Vto) {
  __shared__ __align__(16) short smem[16640];
  short* As = smem;
  short* Bs = smem + 4096;
  const int tid = threadIdx.x;
  const int lane = tid & 63;
  const int wave = tid >> 6;
  const int tn = blockIdx.x;   // 0..47 (tn-fastest: B stays L2-resident)
  const int tm = blockIdx.y;   // 0..63
  const int wr = (wave >> 1) * 64;
  const int wc = (wave & 1) * 64;
  const int lrow = lane & 15;
  const int lk = (lane >> 4) * 8;
  const int K = 256;

  f32x4 acc[4][4];
#pragma unroll
  for (int i = 0; i < 4; ++i)
#pragma unroll
    for (int j = 0; j < 4; ++j) acc[i][j] = (f32x4){0.f, 0.f, 0.f, 0.f};

  const int row_s = tid >> 2;
  const int col_s = (tid & 3) * 8;
  const short* aS = A + (size_t)(tm * 128 + row_s) * K + col_s;
  const short* bS = BT + (size_t)(tn * 128 + row_s) * K + col_s;
  short* AsB = As + wave * 512;
  short* BsB = Bs + wave * 512;

  for (int kt = 0; kt < 8; ++kt) {
    GLL16(aS, AsB);
    GLL16(aS + (size_t)64 * K, AsB + 2048);
    GLL16(bS, BsB);
    GLL16(bS + (size_t)64 * K, BsB + 2048);
    aS += 32; bS += 32;
    __syncthreads();
    bf16x8 af[4], bfr[4];
#pragma unroll
    for (int i = 0; i < 4; ++i) {
      af[i]  = *(const bf16x8*)(As + (wr + i * 16 + lrow) * 32 + lk);
      bfr[i] = *(const bf16x8*)(Bs + (wc + i * 16 + lrow) * 32 + lk);
    }
#pragma unroll
    for (int i = 0; i < 4; ++i)
#pragma unroll
      for (int j = 0; j < 4; ++j)
        acc[i][j] = __builtin_amdgcn_mfma_f32_16x16x32_bf16(af[i], bfr[j], acc[i][j], 0, 0, 0);
    __syncthreads();
  }

  const int rbase = (lane >> 4) * 4;
  if (tn < 32) {
    short* C = (tn < 16) ? Qo : Ko;
    const float sc = (tn < 16) ? 1.f : 0.0625f;   // pre-scale K by 1/sqrt(KD)
    const int cb = (tn & 15) * 128;
#pragma unroll
    for (int j = 0; j < 4; ++j) {
      const int cj = wc + j * 16 + lrow;
      const float bv = bias[tn * 128 + cj];
      const int cl = cb + cj;
#pragma unroll
      for (int i = 0; i < 4; ++i) {
        const int row0 = tm * 128 + wr + i * 16 + rbase;
        f32x4 a = acc[i][j];
#pragma unroll
        for (int r = 0; r < 4; ++r)
          C[(size_t)(row0 + r) * NQKVn + cl] = f2bf((a[r] + bv) * sc);
      }
    }
  } else {
    // V: stage transposed tile in LDS, write Vt coalesced
    __syncthreads();
    short* Ct = smem;  // [128 cols][130]
#pragma unroll
    for (int j = 0; j < 4; ++j) {
      const int colL = wc + j * 16 + lrow;
      const float bv = bias[tn * 128 + colL];
#pragma unroll
      for (int i = 0; i < 4; ++i) {
        const int rowL0 = wr + i * 16 + rbase;
        f32x4 a = acc[i][j];
        short4v o = { f2bf(a[0] + bv), f2bf(a[1] + bv), f2bf(a[2] + bv), f2bf(a[3] + bv) };
        *(short4v*)(&Ct[colL * 130 + rowL0]) = o;
      }
    }
    __syncthreads();
    const int kd_l = tid >> 1;
    const int so = (tid & 1) * 64;
    const int cl = (tn - 32) * 128 + kd_l;
    const int hh = cl >> 8;
    const int kd = cl & 255;
    const int row0 = tm * 128;
    const int bb = row0 >> 12;
    const int s0 = (row0 & (Sn - 1)) + so;
    short* dst = Vto + (size_t)((bb * Hn + hh) * KDn + kd) * Sn + s0;
#pragma unroll
    for (int u = 0; u < 64; u += 8)
      *(bf16x8*)(dst + u) = *(const bf16x8*)(&Ct[kd_l * 130 + so + u]);
  }
}

// ---------------- GEMM 128x128 (FFN1): bf16 relu out, tn-fastest grid ----------------
__global__ __launch_bounds__(256, 2)
void gemm_ffn1(const short* __restrict__ A, const short* __restrict__ BT,
               const float* __restrict__ bias, short* __restrict__ C,
               int N, int K) {
  __shared__ __align__(16) short As[128 * 32];
  __shared__ __align__(16) short Bs[128 * 32];
  const int tid = threadIdx.x;
  const int lane = tid & 63;
  const int wave = tid >> 6;
  const int tn = blockIdx.x;
  const int tm = blockIdx.y;
  const int wr = (wave >> 1) * 64;
  const int wc = (wave & 1) * 64;
  const int lrow = lane & 15;
  const int lk = (lane >> 4) * 8;

  f32x4 acc[4][4];
#pragma unroll
  for (int i = 0; i < 4; ++i)
#pragma unroll
    for (int j = 0; j < 4; ++j) acc[i][j] = (f32x4){0.f, 0.f, 0.f, 0.f};

  const int row_s = tid >> 2;
  const int col_s = (tid & 3) * 8;
  const short* aS = A + (size_t)(tm * 128 + row_s) * K + col_s;
  const short* bS = BT + (size_t)(tn * 128 + row_s) * K + col_s;
  short* AsB = As + wave * 512;
  short* BsB = Bs + wave * 512;

  const int nk = K >> 5;
  for (int kt = 0; kt < nk; ++kt) {
    GLL16(aS, AsB);
    GLL16(aS + (size_t)64 * K, AsB + 2048);
    GLL16(bS, BsB);
    GLL16(bS + (size_t)64 * K, BsB + 2048);
    aS += 32; bS += 32;
    __syncthreads();
    bf16x8 af[4], bfr[4];
#pragma unroll
    for (int i = 0; i < 4; ++i) {
      af[i]  = *(const bf16x8*)(As + (wr + i * 16 + lrow) * 32 + lk);
      bfr[i] = *(const bf16x8*)(Bs + (wc + i * 16 + lrow) * 32 + lk);
    }
#pragma unroll
    for (int i = 0; i < 4; ++i)
#pragma unroll
      for (int j = 0; j < 4; ++j)
        acc[i][j] = __builtin_amdgcn_mfma_f32_16x16x32_bf16(af[i], bfr[j], acc[i][j], 0, 0, 0);
    __syncthreads();
  }

  const int rbase = (lane >> 4) * 4;
#pragma unroll
  for (int j = 0; j < 4; ++j) {
    const int col = tn * 128 + wc + j * 16 + lrow;
    const float bv = bias[col];
#pragma unroll
    for (int i = 0; i < 4; ++i) {
      const int row0 = tm * 128 + wr + i * 16 + rbase;
      f32x4 a = acc[i][j];
#pragma unroll
      for (int r = 0; r < 4; ++r)
        C[(size_t)(row0 + r) * N + col] = f2bf(fmaxf(a[r] + bv, 0.f));
    }
  }
}

// ---------------- GEMM 64x64 tile (skinny N=256): f32 out, tn-fastest grid ----------------
__global__ __launch_bounds__(256, 4)
void gemm_bt64(const short* __restrict__ A, const short* __restrict__ BT,
               const float* __restrict__ bias, float* __restrict__ C,
               int N, int K) {
  __shared__ __align__(16) short As[64 * 32];
  __shared__ __align__(16) short Bs[64 * 32];
  const int tid = threadIdx.x;
  const int lane = tid & 63;
  const int wave = tid >> 6;
  const int tn = blockIdx.x;
  const int tm = blockIdx.y;
  const int wr = (wave >> 1) * 32;
  const int wc = (wave & 1) * 32;
  const int lrow = lane & 15;
  const int lk = (lane >> 4) * 8;

  f32x4 acc[2][2];
#pragma unroll
  for (int i = 0; i < 2; ++i)
#pragma unroll
    for (int j = 0; j < 2; ++j) acc[i][j] = (f32x4){0.f, 0.f, 0.f, 0.f};

  const int row_s = tid >> 2;
  const int col_s = (tid & 3) * 8;
  const short* aS = A + (size_t)(tm * 64 + row_s) * K + col_s;
  const short* bS = BT + (size_t)(tn * 64 + row_s) * K + col_s;
  short* AsB = As + wave * 512;
  short* BsB = Bs + wave * 512;

  const int nk = K >> 5;
  for (int kt = 0; kt < nk; ++kt) {
    GLL16(aS, AsB);
    GLL16(bS, BsB);
    aS += 32; bS += 32;
    __syncthreads();
    bf16x8 af[2], bfr[2];
#pragma unroll
    for (int i = 0; i < 2; ++i) {
      af[i]  = *(const bf16x8*)(As + (wr + i * 16 + lrow) * 32 + lk);
      bfr[i] = *(const bf16x8*)(Bs + (wc + i * 16 + lrow) * 32 + lk);
    }
#pragma unroll
    for (int i = 0; i < 2; ++i)
#pragma unroll
      for (int j = 0; j < 2; ++j)
        acc[i][j] = __builtin_amdgcn_mfma_f32_16x16x32_bf16(af[i], bfr[j], acc[i][j], 0, 0, 0);
    __syncthreads();
  }

  const int rbase = (lane >> 4) * 4;
#pragma unroll
  for (int j = 0; j < 2; ++j) {
    const int col = tn * 64 + wc + j * 16 + lrow;
    const float bv = bias[col];
#pragma unroll
    for (int i = 0; i < 2; ++i) {
      const int row0 = tm * 64 + wr + i * 16 + rbase;
      f32x4 a = acc[i][j];
#pragma unroll
      for (int r = 0; r < 4; ++r) C[(size_t)(row0 + r) * N + col] = a[r] + bv;
    }
  }
}

// ---------------- sliding-window attention, LDS-staged K/V, counted-vmcnt pipeline ----------------
// 1D grid 256 blocks (XCD-swizzled), 512 threads = 8 waves x 32 queries.
// Triple-buffered 32-key chunks; ONE raw s_barrier per chunk; vmcnt(8) keeps
// two prefetched chunks' global_load_lds in flight across barriers (T3/T4).
__global__ __launch_bounds__(512, 1)
void attn_win(const short* __restrict__ q, const short* __restrict__ k,
              const short* __restrict__ vt, short* __restrict__ ctx,
              const int* __restrict__ w2p) {
  const int bid = blockIdx.x;
  const int swz = (bid & 7) * 32 + (bid >> 3);   // 8 XCDs x 32 contiguous blocks
  const int q0 = (swz & 15) * 256;
  const int h = (swz >> 4) & 7;
  const int b = swz >> 7;
  const int tid = threadIdx.x;
  const int lane = tid & 63;
  const int wave = tid >> 6;
  const int w2 = *w2p;
  const int qw = q0 + wave * 32;
  const int lrow = lane & 15;
  const int lk = (lane >> 4) * 8;
  const int lk2 = lk * 2;
  const int rbase = (lane >> 4) * 4;

  __shared__ __align__(16) short Ks[3][8192];   // 32 keys x 256 kd (512B rows, xor (r&7)<<4)
  __shared__ __align__(16) short Vs[3][8192];   // 256 kd x 32 keys (64B rows, xor (r&3)<<4)
  __shared__ __align__(16) short Ps[8][1024];
  short* P = Ps[wave];

  const short* qbase = q + (size_t)(b * Sn + qw) * NQKVn + h * KDn;
  bf16x8 qf[2][8];
#pragma unroll
  for (int mi = 0; mi < 2; ++mi)
#pragma unroll
    for (int ks = 0; ks < 8; ++ks)
      qf[mi][ks] = *(const bf16x8*)(qbase + (size_t)(mi * 16 + lrow) * NQKVn + ks * 32 + lk);

  f32x4 oacc[2][16];
#pragma unroll
  for (int mi = 0; mi < 2; ++mi)
#pragma unroll
    for (int nc = 0; nc < 16; ++nc) oacc[mi][nc] = (f32x4){0.f, 0.f, 0.f, 0.f};

  float lsum[2][4];
#pragma unroll
  for (int mi = 0; mi < 2; ++mi)
#pragma unroll
    for (int r = 0; r < 4; ++r) lsum[mi][r] = 0.f;

  const short* kbase = k + (size_t)(b * Sn) * NQKVn + h * KDn;
  const short* vtb = vt + (size_t)((b * Hn + h) * KDn) * Sn;

  int bstart = q0 - w2; if (bstart < 0) bstart = 0; bstart &= ~31;
  int bend = q0 + 256 + w2; if (bend > Sn) bend = Sn; bend = (bend + 31) & ~31;
  int wlo = qw - w2; if (wlo < 0) wlo = 0; wlo &= ~31;
  int whi = qw + 32 + w2; if (whi > Sn) whi = Sn;

  auto stage = [&](int c0, int bf) {
#pragma unroll
    for (int e = 0; e < 2; ++e) {   // K chunk: 2 x 8KB
      const int o = e * 8192 + tid * 16;
      const int row = o >> 9;
      const int cc = (o & 511) ^ ((row & 7) << 4);
      GLL16(kbase + (size_t)(c0 + row) * NQKVn + (cc >> 1),
            (char*)Ks[bf] + e * 8192 + wave * 1024);
    }
#pragma unroll
    for (int e = 0; e < 2; ++e) {   // V chunk: 2 x 8KB
      const int o = e * 8192 + tid * 16;
      const int row = o >> 6;
      const int cc = (o & 63) ^ ((row & 3) << 4);
      GLL16(vtb + (size_t)row * Sn + c0 + (cc >> 1),
            (char*)Vs[bf] + e * 8192 + wave * 1024);
    }
  };

  const int nch = (bend - bstart) >> 5;
  stage(bstart, 0);
  if (nch > 1) stage(bstart + 32, 1);

  int cur = 0;
  for (int i = 0; i < nch; ++i) {
    const int c0 = bstart + i * 32;
    if (i + 2 < nch) stage(c0 + 64, (cur + 2 >= 3) ? cur - 1 : cur + 2);
    // counted drain: chunk i's 4 loads are the oldest; keep up to 2 chunks (8 loads) flying
    if (i == 0) {
      asm volatile("s_waitcnt vmcnt(0)" ::: "memory");
    } else {
      const int ahead = ((i + 3 < nch) ? i + 3 : nch) - i - 1;  // chunks still in flight after this one
      if (ahead >= 2)      asm volatile("s_waitcnt vmcnt(8)" ::: "memory");
      else if (ahead == 1) asm volatile("s_waitcnt vmcnt(4)" ::: "memory");
      else                 asm volatile("s_waitcnt vmcnt(0)" ::: "memory");
    }
    __builtin_amdgcn_s_barrier();
    asm volatile("" ::: "memory");   // keep LDS reads below the barrier

    if (c0 >= wlo && c0 < whi) {                // wave-uniform skip
      const char* Kc = (const char*)Ks[cur];
      const int x0 = (lrow & 7) << 4;
      f32x4 sf[2][2];
      sf[0][0] = sf[0][1] = sf[1][0] = sf[1][1] = (f32x4){0.f, 0.f, 0.f, 0.f};
#pragma unroll
      for (int ks = 0; ks < 8; ++ks) {
        const int cb = (lk2 + ks * 64) ^ x0;
        bf16x8 kf0 = *(const bf16x8*)(Kc + lrow * 512 + cb);
        bf16x8 kf1 = *(const bf16x8*)(Kc + (16 + lrow) * 512 + cb);
        sf[0][0] = __builtin_amdgcn_mfma_f32_16x16x32_bf16(qf[0][ks], kf0, sf[0][0], 0, 0, 0);
        sf[0][1] = __builtin_amdgcn_mfma_f32_16x16x32_bf16(qf[0][ks], kf1, sf[0][1], 0, 0, 0);
        sf[1][0] = __builtin_amdgcn_mfma_f32_16x16x32_bf16(qf[1][ks], kf0, sf[1][0], 0, 0, 0);
        sf[1][1] = __builtin_amdgcn_mfma_f32_16x16x32_bf16(qf[1][ks], kf1, sf[1][1], 0, 0, 0);
      }
      const bool full = (c0 >= qw + 31 - w2) && (c0 + 31 <= qw + w2);
      if (full) {
#pragma unroll
        for (int mi = 0; mi < 2; ++mi)
#pragma unroll
          for (int ni = 0; ni < 2; ++ni)
#pragma unroll
            for (int r = 0; r < 4; ++r) {
              const float p = __expf(sf[mi][ni][r]);   // K pre-scaled by 1/16
              sf[mi][ni][r] = p;
              lsum[mi][r] += p;
            }
      } else {
#pragma unroll
        for (int mi = 0; mi < 2; ++mi)
#pragma unroll
          for (int ni = 0; ni < 2; ++ni) {
            const int kk = c0 + ni * 16 + lrow;
#pragma unroll
            for (int r = 0; r < 4; ++r) {
              const int dd = (qw + mi * 16 + rbase + r) - kk;
              const bool val = (dd <= w2) && (dd >= -w2);
              float p = __expf(sf[mi][ni][r]);
              p = val ? p : 0.f;
              sf[mi][ni][r] = p;
              lsum[mi][r] += p;
            }
          }
      }
#pragma unroll
      for (int mi = 0; mi < 2; ++mi)
#pragma unroll
        for (int ni = 0; ni < 2; ++ni)
#pragma unroll
          for (int r = 0; r < 4; ++r)
            P[(mi * 16 + rbase + r) * 32 + ni * 16 + lrow] = f2bf(sf[mi][ni][r]);

      bf16x8 pa0 = *(const bf16x8*)(P + lrow * 32 + lk);
      bf16x8 pa1 = *(const bf16x8*)(P + (16 + lrow) * 32 + lk);
      const char* Vc = (const char*)Vs[cur] + lrow * 64 + (lk2 ^ ((lrow & 3) << 4));
#pragma unroll
      for (int nc = 0; nc < 16; ++nc) {
        bf16x8 vf = *(const bf16x8*)(Vc + nc * 1024);
        oacc[0][nc] = __builtin_amdgcn_mfma_f32_16x16x32_bf16(pa0, vf, oacc[0][nc], 0, 0, 0);
        oacc[1][nc] = __builtin_amdgcn_mfma_f32_16x16x32_bf16(pa1, vf, oacc[1][nc], 0, 0, 0);
      }
    }
    cur = (cur == 2) ? 0 : cur + 1;
  }

#pragma unroll
  for (int mi = 0; mi < 2; ++mi)
#pragma unroll
    for (int r = 0; r < 4; ++r) {
      float s = lsum[mi][r];
#pragma unroll
      for (int d = 1; d < 16; d <<= 1) s += __shfl_xor(s, d);
      lsum[mi][r] = 1.f / s;
    }

  short* cbase = ctx + (size_t)(b * Sn + qw) * NQKVn + h * KDn;
#pragma unroll
  for (int mi = 0; mi < 2; ++mi)
#pragma unroll
    for (int nc = 0; nc < 16; ++nc)
#pragma unroll
      for (int r = 0; r < 4; ++r)
        cbase[(size_t)(mi * 16 + rbase + r) * NQKVn + nc * 16 + lrow] =
            f2bf(oacc[mi][nc][r] * lsum[mi][r]);
}

// ---------------- fused residual + LayerNorm (vectorized) ----------------
__global__ __launch_bounds__(256)
void ln_fused(const float* __restrict__ xin, const float* __restrict__ yin,
              const float* __restrict__ g, const float* __restrict__ bb,
              float* __restrict__ of32, short* __restrict__ obf) {
  const int row = blockIdx.x * 4 + (threadIdx.x >> 6);
  const int lane = threadIdx.x & 63;
  const size_t base = (size_t)row * Dn + lane * 4;
  float4 a = *(const float4*)(xin + base);
  float4 bv = *(const float4*)(yin + base);
  float4 v = { a.x + bv.x, a.y + bv.y, a.z + bv.z, a.w + bv.w };
  float sum = v.x + v.y + v.z + v.w;
  float ssq = v.x * v.x + v.y * v.y + v.z * v.z + v.w * v.w;
#pragma unroll
  for (int d = 1; d < 64; d <<= 1) { sum += __shfl_xor(sum, d); ssq += __shfl_xor(ssq, d); }
  const float mu = sum * (1.f / Dn);
  const float var = ssq * (1.f / Dn) - mu * mu;
  const float rs = rsqrtf(var + 1e-3f);
  float4 gg = *(const float4*)(g + lane * 4);
  float4 bbv = *(const float4*)(bb + lane * 4);
  float4 o = { (v.x - mu) * rs * gg.x + bbv.x, (v.y - mu) * rs * gg.y + bbv.y,
               (v.z - mu) * rs * gg.z + bbv.z, (v.w - mu) * rs * gg.w + bbv.w };
  if (of32) *(float4*)(of32 + base) = o;
  if (obf) {
    short4v ob = { f2bf(o.x), f2bf(o.y), f2bf(o.z), f2bf(o.w) };
    *(short4v*)(obf + base) = ob;
  }
}

extern "C" void kernel_launch(void* const* d_in, const int* in_sizes, int n_in,
                              void* d_out, int out_size, void* d_ws, size_t ws_size,
                              hipStream_t stream) {
  const float* x   = (const float*)d_in[0];
  const int*   w2p = (const int*)d_in[1];
  const float* Wq  = (const float*)d_in[2];
  const float* bq  = (const float*)d_in[3];
  const float* Wk  = (const float*)d_in[4];
  const float* bk  = (const float*)d_in[5];
  const float* Wv  = (const float*)d_in[6];
  const float* bv  = (const float*)d_in[7];
  const float* Wo  = (const float*)d_in[8];
  const float* bo  = (const float*)d_in[9];
  const float* W1  = (const float*)d_in[10];
  const float* b1  = (const float*)d_in[11];
  const float* W2  = (const float*)d_in[12];
  const float* b2  = (const float*)d_in[13];
  const float* g1  = (const float*)d_in[14];
  const float* be1 = (const float*)d_in[15];
  const float* g2  = (const float*)d_in[16];
  const float* be2 = (const float*)d_in[17];
  float* out = (float*)d_out;

  char* ws = (char*)d_ws;
  size_t off = 0;
  auto alloc = [&](size_t bytes) { void* p = ws + off; off += (bytes + 255) & ~(size_t)255; return p; };
  short* xb    = (short*)alloc((size_t)Mn * Dn * 2);
  short* WqkvT = (short*)alloc((size_t)3 * NQKVn * Dn * 2);   // [6144][256]
  float* bqkv  = (float*)alloc((size_t)3 * NQKVn * 4);
  short* WoT   = (short*)alloc((size_t)Dn * NQKVn * 2);
  short* W1T   = (short*)alloc((size_t)DFFn * Dn * 2);
  short* W2T   = (short*)alloc((size_t)Dn * DFFn * 2);
  short* qb    = (short*)alloc((size_t)Mn * NQKVn * 2);
  short* kb    = (short*)alloc((size_t)Mn * NQKVn * 2);
  short* vtb   = (short*)alloc((size_t)Mn * NQKVn * 2);
  float* attn_out = (float*)alloc((size_t)Mn * Dn * 4);
  float* x1    = (float*)alloc((size_t)Mn * Dn * 4);
  // stream-ordered safe aliases
  short* ctxb = qb;
  short* x1b  = xb;
  short* hb   = kb;
  float* ffn  = attn_out;

  cvt_x<<<dim3(Mn * Dn / 1024), dim3(256), 0, stream>>>(x, xb, Mn * Dn);
  cvt_weights<<<dim3(2560), dim3(256), 0, stream>>>(
      Wq, Wk, Wv, Wo, W1, W2,
      WqkvT, WqkvT + (size_t)NQKVn * Dn, WqkvT + (size_t)2 * NQKVn * Dn,
      WoT, W1T, W2T);
  concat_bias<<<dim3(24), dim3(256), 0, stream>>>(bq, bk, bv, bqkv);

  gemm_qkv<<<dim3(48, 64), dim3(256), 0, stream>>>(xb, WqkvT, bqkv, qb, kb, vtb);

  attn_win<<<dim3(256), dim3(512), 0, stream>>>(qb, kb, vtb, ctxb, w2p);

  gemm_bt64<<<dim3(Dn / 64, Mn / 64), dim3(256), 0, stream>>>(ctxb, WoT, bo, attn_out, Dn, NQKVn);
  ln_fused<<<dim3(Mn / 4), dim3(256), 0, stream>>>(x, attn_out, g1, be1, x1, x1b);
  gemm_ffn1<<<dim3(DFFn / 128, Mn / 128), dim3(256), 0, stream>>>(x1b, W1T, b1, hb, DFFn, Dn);
  gemm_bt64<<<dim3(Dn / 64, Mn / 64), dim3(256), 0, stream>>>(hb, W2T, b2, ffn, Dn, DFFn);
  ln_fused<<<dim3(Mn / 4), dim3(256), 0, stream>>>(x1, ffn, g2, be2, out, (short*)nullptr);
}